// Round 1
// baseline (545.145 us; speedup 1.0000x reference)
//
#include <hip/hip_runtime.h>
#include <math.h>

#define FLAT 12288
#define NH   4096
#define KSTEPS 4
#define LRC 0.01f
#define NSEG 384       // segments for the fp32 colpart pass (RPS rows each)
#define RPS  32        // NSEG * RPS == FLAT
#define NSEGF 768      // segments written by the fused v+colpart kernel (16 rows each)
#define WSCALE 64.0f
#define WINV   0.015625f

typedef float v2f __attribute__((ext_vector_type(2)));

__device__ __forceinline__ float sigm(float x) {
    return __builtin_amdgcn_rcpf(1.0f + __expf(-x));
}

// ---- DPP wave64 sum: result valid in lane 63 ----
template <int CTRL>
__device__ __forceinline__ float dpp_add(float x) {
    int s = __builtin_amdgcn_update_dpp(0, __float_as_int(x), CTRL, 0xf, 0xf, true);
    return x + __int_as_float(s);
}
__device__ __forceinline__ float wave_sum63(float x) {
    x = dpp_add<0x111>(x);  // row_shr:1
    x = dpp_add<0x112>(x);  // row_shr:2
    x = dpp_add<0x114>(x);  // row_shr:4
    x = dpp_add<0x118>(x);  // row_shr:8
    x = dpp_add<0x142>(x);  // row_bcast:15
    x = dpp_add<0x143>(x);  // row_bcast:31
    return x;               // lane 63 holds the full sum
}

// 16-col fp8 dot with h. NOTE: fixed the hc.w / hd.w terms (old kernel used
// hc.z / hd.z twice -> every 8th column multiplied its neighbor's h).
__device__ __forceinline__ float dot16(uint4 w, const float4* __restrict__ h4, int k) {
    float4 ha = h4[4*k+0], hb = h4[4*k+1], hc = h4[4*k+2], hd = h4[4*k+3];
    v2f f; float d = 0.f;
    f = __builtin_amdgcn_cvt_pk_f32_fp8(w.x, false); d = fmaf(f.x, ha.x, d); d = fmaf(f.y, ha.y, d);
    f = __builtin_amdgcn_cvt_pk_f32_fp8(w.x, true);  d = fmaf(f.x, ha.z, d); d = fmaf(f.y, ha.w, d);
    f = __builtin_amdgcn_cvt_pk_f32_fp8(w.y, false); d = fmaf(f.x, hb.x, d); d = fmaf(f.y, hb.y, d);
    f = __builtin_amdgcn_cvt_pk_f32_fp8(w.y, true);  d = fmaf(f.x, hb.z, d); d = fmaf(f.y, hb.w, d);
    f = __builtin_amdgcn_cvt_pk_f32_fp8(w.z, false); d = fmaf(f.x, hc.x, d); d = fmaf(f.y, hc.y, d);
    f = __builtin_amdgcn_cvt_pk_f32_fp8(w.z, true);  d = fmaf(f.x, hc.z, d); d = fmaf(f.y, hc.w, d);
    f = __builtin_amdgcn_cvt_pk_f32_fp8(w.w, false); d = fmaf(f.x, hd.x, d); d = fmaf(f.y, hd.y, d);
    f = __builtin_amdgcn_cvt_pk_f32_fp8(w.w, true);  d = fmaf(f.x, hd.z, d); d = fmaf(f.y, hd.w, d);
    return d;
}

// accumulate vs * (16 fp8 cols) into acc[0..15]
__device__ __forceinline__ void accum16(uint4 w, float vs, float* acc) {
    v2f f;
    f = __builtin_amdgcn_cvt_pk_f32_fp8(w.x, false); acc[0]  = fmaf(f.x, vs, acc[0]);  acc[1]  = fmaf(f.y, vs, acc[1]);
    f = __builtin_amdgcn_cvt_pk_f32_fp8(w.x, true);  acc[2]  = fmaf(f.x, vs, acc[2]);  acc[3]  = fmaf(f.y, vs, acc[3]);
    f = __builtin_amdgcn_cvt_pk_f32_fp8(w.y, false); acc[4]  = fmaf(f.x, vs, acc[4]);  acc[5]  = fmaf(f.y, vs, acc[5]);
    f = __builtin_amdgcn_cvt_pk_f32_fp8(w.y, true);  acc[6]  = fmaf(f.x, vs, acc[6]);  acc[7]  = fmaf(f.y, vs, acc[7]);
    f = __builtin_amdgcn_cvt_pk_f32_fp8(w.z, false); acc[8]  = fmaf(f.x, vs, acc[8]);  acc[9]  = fmaf(f.y, vs, acc[9]);
    f = __builtin_amdgcn_cvt_pk_f32_fp8(w.z, true);  acc[10] = fmaf(f.x, vs, acc[10]); acc[11] = fmaf(f.y, vs, acc[11]);
    f = __builtin_amdgcn_cvt_pk_f32_fp8(w.w, false); acc[12] = fmaf(f.x, vs, acc[12]); acc[13] = fmaf(f.y, vs, acc[13]);
    f = __builtin_amdgcn_cvt_pk_f32_fp8(w.w, true);  acc[14] = fmaf(f.x, vs, acc[14]); acc[15] = fmaf(f.y, vs, acc[15]);
}

// ================= Phase A =================

// Pass 0: read fp32 W, emit column partials for h1, convert W -> fp8 (x64).
// grid (4, NSEG), block 256; 4 cols/thread.
__global__ __launch_bounds__(256) void k_colpart_cvt(const float* __restrict__ W,
                                                     const float* __restrict__ v,
                                                     float* __restrict__ partials,
                                                     unsigned int* __restrict__ W8) {
    const float4* W4 = (const float4*)W;
    int c4 = blockIdx.x * 256 + threadIdx.x;           // [0,1024)
    int r0 = blockIdx.y * RPS;
    float4 acc = make_float4(0.f, 0.f, 0.f, 0.f);
    for (int r = r0; r < r0 + RPS; ++r) {
        float vr = v[r];
        float4 w = W4[(size_t)r * (NH / 4) + c4];
        acc.x = fmaf(w.x, vr, acc.x);
        acc.y = fmaf(w.y, vr, acc.y);
        acc.z = fmaf(w.z, vr, acc.z);
        acc.w = fmaf(w.w, vr, acc.w);
        unsigned int p = 0;
        p = __builtin_amdgcn_cvt_pk_fp8_f32(w.x * WSCALE, w.y * WSCALE, p, false);
        p = __builtin_amdgcn_cvt_pk_fp8_f32(w.z * WSCALE, w.w * WSCALE, p, true);
        W8[(size_t)r * (NH / 4) + c4] = p;
    }
    ((float4*)partials)[(size_t)blockIdx.y * (NH / 4) + c4] = acc;
}

// h[col] = sigm(b + sum over nseg partials). grid NH/32, block 256 (32 cols x 8 seg-threads).
__global__ __launch_bounds__(256) void k_hreduce(const float* __restrict__ partials,
                                                 const float* __restrict__ b,
                                                 float* __restrict__ h,
                                                 float* __restrict__ hi,
                                                 int nseg) {
    int c  = threadIdx.x & 31;
    int sg = threadIdx.x >> 5;                          // 0..7
    int col = blockIdx.x * 32 + c;
    float s = 0.f;
    for (int g = sg; g < nseg; g += 8) s += partials[(size_t)g * NH + col];
    __shared__ float red[8][33];
    red[sg][c] = s;
    __syncthreads();
    if (threadIdx.x < 32) {
        float t = 0.f;
#pragma unroll
        for (int g2 = 0; g2 < 8; g2++) t += red[g2][threadIdx.x];
        float hh = sigm(t + b[col]);
        h[col] = hh;
        if (hi) hi[col] = hh;
    }
}

// FUSED v-step + column-partials: per row, compute v_r = sigm(a + W8[row,:].h/64),
// then immediately reuse the fp8 row (still in registers) to accumulate
// v_r * W8[row,:] into per-lane column partials for the NEXT h.
// Saves one full 48 MB W8 pass per Gibbs step.
// grid FLAT/16 = 768 blocks, block 256 (4 waves x 4 rows each).
__global__ __launch_bounds__(256) void k_vh_fused(const unsigned char* __restrict__ W8,
                                                  const float* __restrict__ h,
                                                  const float* __restrict__ a,
                                                  float* __restrict__ partials) {
    int lane = threadIdx.x & 63, wid = threadIdx.x >> 6;
    int row0 = blockIdx.x * 16 + wid * 4;
    const float4* h4 = (const float4*)h;
    __shared__ float pbuf[2][NH];                      // 32 KiB

    // acc[16*i + j] <-> column 16*(lane + 64*i) + j
    float acc[64];
#pragma unroll
    for (int i = 0; i < 64; i++) acc[i] = 0.f;

    for (int rr = 0; rr < 4; ++rr) {
        int row = row0 + rr;
        const uint4* Wr = (const uint4*)(W8 + (size_t)row * NH);
        uint4 w0 = Wr[lane], w1 = Wr[lane + 64], w2 = Wr[lane + 128], w3 = Wr[lane + 192];
        float d0 = dot16(w0, h4, lane);
        float d1 = dot16(w1, h4, lane + 64);
        float d2 = dot16(w2, h4, lane + 128);
        float d3 = dot16(w3, h4, lane + 192);
        float s = wave_sum63((d0 + d1) + (d2 + d3));
        s = __int_as_float(__builtin_amdgcn_readlane(__float_as_int(s), 63));
        float vr = sigm(a[row] + s * WINV);
        float vs = vr * WINV;                          // fold fp8 descale into v
        accum16(w0, vs, acc);
        accum16(w1, vs, acc + 16);
        accum16(w2, vs, acc + 32);
        accum16(w3, vs, acc + 48);
    }

    // 2-stage cross-wave reduce: waves 0,1 deposit; waves 2,3 add in place.
    if (wid < 2) {
#pragma unroll
        for (int i = 0; i < 4; i++) {
            float4* dst = (float4*)&pbuf[wid][16 * (lane + 64 * i)];
            dst[0] = make_float4(acc[16*i+0],  acc[16*i+1],  acc[16*i+2],  acc[16*i+3]);
            dst[1] = make_float4(acc[16*i+4],  acc[16*i+5],  acc[16*i+6],  acc[16*i+7]);
            dst[2] = make_float4(acc[16*i+8],  acc[16*i+9],  acc[16*i+10], acc[16*i+11]);
            dst[3] = make_float4(acc[16*i+12], acc[16*i+13], acc[16*i+14], acc[16*i+15]);
        }
    }
    __syncthreads();
    if (wid >= 2) {
#pragma unroll
        for (int i = 0; i < 4; i++) {
            float4* p = (float4*)&pbuf[wid - 2][16 * (lane + 64 * i)];
#pragma unroll
            for (int q = 0; q < 4; q++) {
                float4 t = p[q];
                t.x += acc[16*i + 4*q + 0];
                t.y += acc[16*i + 4*q + 1];
                t.z += acc[16*i + 4*q + 2];
                t.w += acc[16*i + 4*q + 3];
                p[q] = t;
            }
        }
    }
    __syncthreads();
    {
        int c0 = threadIdx.x * 16;
        float4* out4 = (float4*)(partials + (size_t)blockIdx.x * NH + c0);
        const float4* p0 = (const float4*)&pbuf[0][c0];
        const float4* p1 = (const float4*)&pbuf[1][c0];
#pragma unroll
        for (int q = 0; q < 4; q++) {
            float4 x = p0[q], y = p1[q];
            x.x += y.x; x.y += y.y; x.z += y.z; x.w += y.w;
            out4[q] = x;
        }
    }
}

// final v-step only (no partials needed after h4): one wave per row.
// grid FLAT/4, block 256.
__global__ __launch_bounds__(256) void k_vstep_fp8(const unsigned char* __restrict__ W8,
                                                   const float* __restrict__ h,
                                                   const float* __restrict__ a,
                                                   float* __restrict__ v) {
    int wid = threadIdx.x >> 6, lane = threadIdx.x & 63;
    int row = blockIdx.x * 4 + wid;
    const uint4* Wr = (const uint4*)(W8 + (size_t)row * NH);
    const float4* h4 = (const float4*)h;
    float acc = 0.f;
    for (int k = lane; k < NH / 16; k += 64) {          // 4 iters
        acc += dot16(Wr[k], h4, k);
    }
    acc = wave_sum63(acc);
    if (lane == 63) v[row] = sigm(a[row] + acc * WINV);
}

// ================= Phase B (unchanged) =================

#define TB  512
#define RVB (FLAT / TB)   // 24
#define RHB (NH / TB)     // 8
#define NWAVES (TB / 64)  // 8

__global__ __launch_bounds__(512) void k_phaseB(const float* __restrict__ inputs,
                                                const float* __restrict__ hi0,
                                                const float* __restrict__ hk0,
                                                const float* __restrict__ vk0,
                                                float* __restrict__ out) {
    int t = threadIdx.x;
    int lane = t & 63, wid = t >> 6;
    __shared__ float2 red[2][NWAVES];   // 2 x 8 x float2 = contiguous 128 B

    float Vi[RVB], Vk[RVB], v[RVB], Vn[RVB];
    float Hi[RHB], Hk[RHB], h[RHB], hini[RHB];

#pragma unroll
    for (int r = 0; r < RVB; r++) { int i = r * TB + t; Vi[r] = inputs[i]; Vk[r] = vk0[i]; }
#pragma unroll
    for (int r = 0; r < RHB; r++) { int j = r * TB + t; Hi[r] = hi0[j]; Hk[r] = hk0[j]; }

    int rc = 0;
    for (int s = 1; s < 16; ++s) {
        const float* vin = inputs + (size_t)s * FLAT;
#pragma unroll
        for (int r = 0; r < RVB; r++) { Vn[r] = vin[r * TB + t]; v[r] = Vn[r]; }

        for (int k = 0; k < KSTEPS; ++k) {
            // alpha = Vi.v, beta = Vk.v   (4-way split chains: dep depth 6)
            float px0 = 0.f, px1 = 0.f, px2 = 0.f, px3 = 0.f;
            float py0 = 0.f, py1 = 0.f, py2 = 0.f, py3 = 0.f;
#pragma unroll
            for (int r = 0; r < RVB; r += 4) {
                px0 = fmaf(Vi[r],   v[r],   px0); py0 = fmaf(Vk[r],   v[r],   py0);
                px1 = fmaf(Vi[r+1], v[r+1], px1); py1 = fmaf(Vk[r+1], v[r+1], py1);
                px2 = fmaf(Vi[r+2], v[r+2], px2); py2 = fmaf(Vk[r+2], v[r+2], py2);
                px3 = fmaf(Vi[r+3], v[r+3], px3); py3 = fmaf(Vk[r+3], v[r+3], py3);
            }
            float px = wave_sum63((px0 + px1) + (px2 + px3));
            float py = wave_sum63((py0 + py1) + (py2 + py3));
            if (lane == 63) { float2 w2; w2.x = px; w2.y = py; red[rc & 1][wid] = w2; }
            __syncthreads();
            float al, be;
            {   // read 8 float2 as 4 float4 (fewer LDS ops on the critical path)
                const float4* R4 = (const float4*)&red[rc & 1][0];
                float4 r0 = R4[0], r1 = R4[1], r2 = R4[2], r3 = R4[3];
                al = (r0.x + r1.x) + (r2.x + r3.x) + ((r0.z + r1.z) + (r2.z + r3.z));
                be = (r0.y + r1.y) + (r2.y + r3.y) + ((r0.w + r1.w) + (r2.w + r3.w));
            }
            rc++;
            float ca = LRC * (1.f + al), cb = LRC * (1.f + be);

            // h = sigm(LR((1+al)Hi - (1+be)Hk)); gamma = Hi.h, delta = Hk.h
            float qx0 = 0.f, qx1 = 0.f, qy0 = 0.f, qy1 = 0.f;
#pragma unroll
            for (int r = 0; r < RHB; r += 2) {
                float h0 = sigm(ca * Hi[r]   - cb * Hk[r]);
                float h1 = sigm(ca * Hi[r+1] - cb * Hk[r+1]);
                h[r] = h0; h[r+1] = h1;
                if (k == 0) { hini[r] = h0; hini[r+1] = h1; }
                qx0 = fmaf(Hi[r],   h0, qx0); qy0 = fmaf(Hk[r],   h0, qy0);
                qx1 = fmaf(Hi[r+1], h1, qx1); qy1 = fmaf(Hk[r+1], h1, qy1);
            }
            float qx = wave_sum63(qx0 + qx1), qy = wave_sum63(qy0 + qy1);
            if (lane == 63) { float2 w2; w2.x = qx; w2.y = qy; red[rc & 1][wid] = w2; }
            __syncthreads();
            float ga, de;
            {
                const float4* R4 = (const float4*)&red[rc & 1][0];
                float4 r0 = R4[0], r1 = R4[1], r2 = R4[2], r3 = R4[3];
                ga = (r0.x + r1.x) + (r2.x + r3.x) + ((r0.z + r1.z) + (r2.z + r3.z));
                de = (r0.y + r1.y) + (r2.y + r3.y) + ((r0.w + r1.w) + (r2.w + r3.w));
            }
            rc++;
            float cg = LRC * (1.f + ga), cd = LRC * (1.f + de);

            // v = sigm(LR((1+ga)Vi - (1+de)Vk))
#pragma unroll
            for (int r = 0; r < RVB; r++) v[r] = sigm(cg * Vi[r] - cd * Vk[r]);
        }

        // rotate carry (Vi <- this sample's input, already in registers)
#pragma unroll
        for (int r = 0; r < RVB; r++) { Vk[r] = v[r]; Vi[r] = Vn[r]; }
#pragma unroll
        for (int r = 0; r < RHB; r++) { Hk[r] = h[r]; Hi[r] = hini[r]; }
    }

#pragma unroll
    for (int r = 0; r < RVB; r++) out[r * TB + t] = Vk[r];
}

// ================= launch =================

extern "C" void kernel_launch(void* const* d_in, const int* in_sizes, int n_in,
                              void* d_out, int out_size, void* d_ws, size_t ws_size,
                              hipStream_t stream) {
    const float* inputs = (const float*)d_in[0];
    const float* W      = (const float*)d_in[1];
    const float* a_in   = (const float*)d_in[2];
    const float* b_in   = (const float*)d_in[3];
    float* out = (float*)d_out;

    // ws layout: W8 (48 MiB) | partials (NSEGF*NH = 12 MiB) | h | hi | v
    unsigned int* W8 = (unsigned int*)d_ws;
    float* partials = (float*)((char*)d_ws + (size_t)FLAT * NH);
    float* h  = partials + (size_t)NSEGF * NH;
    float* hi = h + NH;
    float* v  = hi + NH;

    dim3 blk(256);

    // Sample 0, Gibbs step 1 (h1 == h_init) + W -> fp8 conversion
    k_colpart_cvt<<<dim3(4, NSEG), blk, 0, stream>>>(W, inputs, partials, W8);
    k_hreduce<<<dim3(NH / 32), blk, 0, stream>>>(partials, b_in, h, hi, NSEG);

    // Gibbs steps: fused v-step + column partials for h2..h4 (one W8 pass each)
    for (int k = 1; k < KSTEPS; ++k) {
        k_vh_fused<<<dim3(FLAT / 16), blk, 0, stream>>>((const unsigned char*)W8, h, a_in, partials);
        k_hreduce<<<dim3(NH / 32), blk, 0, stream>>>(partials, b_in, h, (float*)nullptr, NSEGF);
    }

    // final v-step (v4) — no further partials needed
    k_vstep_fp8<<<dim3(FLAT / 4), blk, 0, stream>>>((const unsigned char*)W8, h, a_in, v);

    // Samples 1..15 (rank-2 W), writes final reconstruction
    k_phaseB<<<1, TB, 0, stream>>>(inputs, hi, h, v, out);
}